// Round 24
// baseline (36.085 us; speedup 1.0000x reference)
//
#include <hip/hip_runtime.h>
#include <math.h>

#define CDIM   862
#define NRANK  8
#define KW     7
#define ROWS_PER_BLOCK 4
#define THREADS (ROWS_PER_BLOCK * 64)
#define LN_EPS 1e-5f
#define NTILE  7             // 7 quad-tiles x 128 elements cover [-1,894] >= [0,861]
#define XH_LEN 912           // shorts: [0..3]=x[-4..-1]=0, [4+i]=bf16(x[i]), zeros to 911
#define XY_LEN 866           // f32: x (overwritten by pre-norm y) + pad

typedef __attribute__((ext_vector_type(8)))  short bf16x8;
typedef __attribute__((ext_vector_type(16))) float f32x16;

static __device__ __forceinline__ unsigned rne_bf16(float f) {
    const unsigned u = __float_as_uint(f);
    return (u + 0x7FFFu + ((u >> 16) & 1u)) >> 16;   // round-to-nearest-even
}

// v_exp_f32 IS 2^x on gfx950 (r20-validated). Fallback exact.
#if __has_builtin(__builtin_amdgcn_exp2f)
#define EXP2F(x) __builtin_amdgcn_exp2f(x)
#else
#define EXP2F(x) __expf((x) * 0.69314718055994530942f)
#endif

// One wave = one row. Shuffle-free quad-tile MFMA (r23-validated, PASS
// absmax 0.03125 @36.0us). THIS ROUND: full #pragma unroll on the 7-tile
// loop -- bit-identical semantics (per-lane op order preserved), but the
// scheduler sees all 7 windows/MFMAs/dp8 chains at once and can hoist the
// ds_reads of tile s+1 under tile s's compute (the rolled loop at VGPR=60
// serialized each tile's ds_read->MFMA->exp chain; duty cycle ~44%).
// r21/r23 proved instruction-content cuts don't move time; r8/r12/r22
// proved wave-count doesn't; static in-wave ILP is the last untested lever.
__global__ __launch_bounds__(THREADS) void cvmc_kernel(
    const float* __restrict__ x,
    const float* __restrict__ Wup,
    const float* __restrict__ bup,
    const float* __restrict__ Wdown,
    const float* __restrict__ bdown,
    const float* __restrict__ gamma,
    const float* __restrict__ beta,
    float* __restrict__ out)
{
    const int lane = threadIdx.x & 63;
    const int wv   = threadIdx.x >> 6;
    const int row  = blockIdx.x * ROWS_PER_BLOCK + wv;

    __shared__ short sxh[ROWS_PER_BLOCK][XH_LEN];
    __shared__ float sxy[ROWS_PER_BLOCK][XY_LEN];

    const int hh  = lane >> 5;
    const int l31 = lane & 31;

    // all 8 rank weights per lane (wave-uniform -> SGPR)
    float bu8[NRANK], wd8[NRANK];
#pragma unroll
    for (int q = 0; q < NRANK; ++q) {
        bu8[q] = bup[q];
        wd8[q] = Wdown[q];
    }

    // ---- A fragment: row = l31, k-slot k = 8*hh + j (r23-verified mapping) ----
    bf16x8 afrag;
    {
        const int  rr   = (l31 & 3) + 4 * ((l31 >> 3) & 1);
        const int  sft  = (l31 >> 2) & 1;
        const bool use  = ((l31 >> 4) == hh);
#pragma unroll
        for (int j = 0; j < 8; ++j) {
            const int tap = j - sft;
            float wvv = (use && tap >= 0 && tap < KW) ? Wup[rr * KW + tap] : 0.0f;
            afrag[j] = (short)(rne_bf16(wvv) & 0xFFFFu);
        }
    }

    // ---- C operand: bias; rank of reg q is q&7 for every lane ----
    f32x16 cin;
#pragma unroll
    for (int i = 0; i < 16; ++i) cin[i] = bu8[i & 7];

    // ---- stage row: sxy = f32 x, sxh = bf16(RNE), pads zeroed ----
    {
        const float2* __restrict__ xr2 =
            reinterpret_cast<const float2*>(x + (size_t)row * CDIM);
        unsigned* xhW = reinterpret_cast<unsigned*>(&sxh[wv][0]);
#pragma unroll
        for (int qq = 0; qq < 7; ++qq) {
            const int i = lane + 64 * qq;               // float2 pair index
            if (i < CDIM / 2) {
                float2 v = xr2[i];
                *reinterpret_cast<float2*>(&sxy[wv][2 * i]) = v;
                xhW[2 + i] = rne_bf16(v.x) | (rne_bf16(v.y) << 16);
            }
        }
        if (lane < 2)        xhW[lane] = 0u;            // shorts 0..3 = x[-4..-1]
        else if (lane < 25)  xhW[431 + lane] = 0u;      // dwords 433..455 zero
        else if (lane < 29)  sxy[wv][862 + (lane - 25)] = 0.0f;
    }
    // wave-private LDS slice; same-wave DS ops complete in issue order -> no barrier

    // gelu(t) ~ t*sigmoid(1.5957691 t + 0.0713548 t^3); u = 1 + 2^z (log2e folded)
    const float C1 = -0.0713548162f * 1.44269504088896340736f;
    const float C0 = -1.5957691216f * 1.44269504088896340736f;

    const unsigned* xhD = reinterpret_cast<const unsigned*>(&sxh[wv][0]);

    // full 8-rank GELU + down-proj, lane-local (rank-paired rcp as r15-r23)
    auto dp8 = [&](const float* t) -> float {
        float u[NRANK];
#pragma unroll
        for (int r = 0; r < NRANK; ++r) {
            const float z = t[r] * fmaf(t[r] * t[r], C1, C0);
            u[r] = 1.0f + EXP2F(z);
        }
        float h = 0.0f;
#pragma unroll
        for (int rp = 0; rp < NRANK / 2; ++rp) {
            const float ua = u[2 * rp], ub = u[2 * rp + 1];
            const float rr = __builtin_amdgcn_rcpf(ua * ub);
            float n = (wd8[2 * rp] * t[2 * rp]) * ub;
            n = fmaf(wd8[2 * rp + 1] * t[2 * rp + 1], ua, n);
            h = fmaf(n, rr, h);
        }
        return h;
    };

    float sum = 0.0f, sumsq = 0.0f;

#pragma unroll
    for (int s = 0; s < NTILE; ++s) {
        // this lane's window: 4 aligned dwords (8 bf16) -- its k-half of column l31
        const int w = 64 * s + lane;
        union { unsigned u[4]; bf16x8 v; } bfr;
        bfr.u[0] = xhD[w];
        bfr.u[1] = xhD[w + 1];
        bfr.u[2] = xhD[w + 2];
        bfr.u[3] = xhD[w + 3];

        f32x16 d = __builtin_amdgcn_mfma_f32_32x32x16_bf16(afrag, bfr.v, cin, 0, 0, 0);

        float t0[NRANK], t1[NRANK];
#pragma unroll
        for (int r = 0; r < NRANK; ++r) { t0[r] = d[r]; t1[r] = d[8 + r]; }

        const float h0 = dp8(t0);      // all 8 ranks of eS0 -- no shuffle
        const float h1 = dp8(t1);      // all 8 ranks of eS0+64

        const int eS0 = 128 * s + 2 * l31 - 1 + hh;   // hh=0: E0 (odd), hh=1: E1 (even)
        const int eS1 = eS0 + 64;

        if ((unsigned)eS0 < CDIM) {
            const float y = sxy[wv][eS0] + h0;
            sxy[wv][eS0] = y;
            sum += y;
            sumsq = fmaf(y, y, sumsq);
        }
        if ((unsigned)eS1 < CDIM) {
            const float y = sxy[wv][eS1] + h1;
            sxy[wv][eS1] = y;
            sum += y;
            sumsq = fmaf(y, y, sumsq);
        }
    }

    // in-wave butterfly: every lane ends with the row totals
#pragma unroll
    for (int off = 1; off < 64; off <<= 1) {
        sum   += __shfl_xor(sum, off, 64);
        sumsq += __shfl_xor(sumsq, off, 64);
    }

    const float inv  = 1.0f / (float)CDIM;
    const float mu   = sum * inv;
    const float var  = fmaf(sumsq, inv, -mu * mu);
    const float rstd = rsqrtf(var + LN_EPS);

    // coalesced epilogue: contiguous float2 reads from LDS, float2 stores
    float2* __restrict__ yr2 = reinterpret_cast<float2*>(out + (size_t)row * CDIM);
    const float2* __restrict__ g2 = reinterpret_cast<const float2*>(gamma);
    const float2* __restrict__ b2 = reinterpret_cast<const float2*>(beta);
#pragma unroll
    for (int qq = 0; qq < 7; ++qq) {
        const int i = lane + 64 * qq;
        if (i < CDIM / 2) {
            const float2 yv = *reinterpret_cast<const float2*>(&sxy[wv][2 * i]);
            const float2 gv = g2[i];
            const float2 bv = b2[i];
            float2 o;
            o.x = fmaf((yv.x - mu) * rstd, gv.x, bv.x);
            o.y = fmaf((yv.y - mu) * rstd, gv.y, bv.y);
            yr2[i] = o;
        }
    }
}

extern "C" void kernel_launch(void* const* d_in, const int* in_sizes, int n_in,
                              void* d_out, int out_size, void* d_ws, size_t ws_size,
                              hipStream_t stream) {
    const float* x     = (const float*)d_in[0];
    const float* Wup   = (const float*)d_in[1];
    const float* bup   = (const float*)d_in[2];
    const float* Wdown = (const float*)d_in[3];
    const float* bdown = (const float*)d_in[4];   // cancels in LayerNorm; unused
    const float* gamma = (const float*)d_in[5];
    const float* beta  = (const float*)d_in[6];
    float* out = (float*)d_out;
    (void)bdown;

    const int nrows = out_size / CDIM;                 // 11520 (divisible by 4)
    const int nblk  = nrows / ROWS_PER_BLOCK;          // 2880
    cvmc_kernel<<<nblk, THREADS, 0, stream>>>(x, Wup, bup, Wdown, bdown,
                                              gamma, beta, out);
}